// Round 5
// baseline (221.956 us; speedup 1.0000x reference)
//
#include <hip/hip_runtime.h>
#include <hip/hip_cooperative_groups.h>
#include <math.h>

namespace cg = cooperative_groups;

#define N_ANCH 87296
#define NCLS 91
#define NBINS 4096
#define K_CAND 256
#define CAP 512
#define MAX_OUT 100
#define IOU_TH 0.6f
#define NB 682          // blocks (N_ANCH / 128)
#define BT 128          // threads per block (2 waves)

// ws layout (bytes):
//      0: hist   (NBINS*4 = 16384)
//  16384: cnt    (4)
//  16400: gcs    (CAP*4 = 2048)   candidate scores
//  18448: gcidx  (CAP*4 = 2048)   candidate anchor indices

__device__ __forceinline__ float sigmoidf_(float x) {
    return 1.0f / (1.0f + expf(-x));
}

__global__ void __launch_bounds__(BT)
fcos_all_kernel(const float* __restrict__ logits,
                const float* __restrict__ boxreg,
                const float* __restrict__ ctr,
                const float* __restrict__ anchors,
                float* __restrict__ out,
                unsigned* __restrict__ hist,
                unsigned* __restrict__ cnt,
                float* __restrict__ gcs,
                int* __restrict__ gcidx) {
    cg::grid_group grid = cg::this_grid();

    // staging pool (46592 B); block 0 reuses it for NMS state after scoring
    __shared__ float pool[2 * 64 * 91];
    __shared__ float s_best[2];
    __shared__ int   s_bid[2];
    __shared__ int   s_fb;

    const int tid  = threadIdx.x;
    const int lane = tid & 63;
    const int w    = tid >> 6;
    const int bid  = blockIdx.x;

    // ---- zero hist + counter (done by blocks 0..31, visible after sync #1) --
    if (bid < NBINS / BT) hist[bid * BT + tid] = 0u;
    if (bid == 0 && tid == 0) *cnt = 0u;

    // ---- score: wave-cooperative coalesced staging, 1 row/thread ----
    const int rowbase = bid * BT + w * 64;
    const float4* g4 = (const float4*)logits + (size_t)rowbase * 91 / 4;
    float4* l4 = (float4*)(pool + w * 5824);
    #pragma unroll
    for (int k = 0; k < 23; ++k) {
        int idx = k * 64 + lane;
        if (idx < 1456) l4[idx] = g4[idx];
    }
    __syncthreads();

    const int i = bid * BT + tid;
    const float* row = pool + w * 5824 + lane * 91;
    float m = row[0];
    #pragma unroll
    for (int j = 1; j < NCLS; ++j) m = fmaxf(m, row[j]);
    const float s = sqrtf(sigmoidf_(m) * sigmoidf_(ctr[i]));
    const int bin = min(max((int)(s * (float)NBINS), 0), NBINS - 1);
    __syncthreads();   // pool reads done before block 0 may reuse it later

    grid.sync();   // #1: hist zeroed everywhere
    atomicAdd(&hist[bin], 1u);
    grid.sync();   // #2: hist complete

    // ---- threshold: wave 0 of EVERY block (redundant; avoids a bcast sync) --
    if (tid < 64) {
        const uint4* h4 = (const uint4*)hist;    // 1024 uint4
        uint4 c[16];
        #pragma unroll
        for (int q = 0; q < 16; ++q) c[q] = h4[lane * 16 + q];

        unsigned local = 0;
        #pragma unroll
        for (int q = 0; q < 16; ++q) local += c[q].x + c[q].y + c[q].z + c[q].w;

        unsigned p = local;                       // suffix-inclusive scan
        #pragma unroll
        for (int d = 1; d < 64; d <<= 1) {
            unsigned t = (unsigned)__shfl_down((int)p, d, 64);
            if (lane + d < 64) p += t;
        }
        unsigned long long mask = __ballot(p >= K_CAND);
        int L = 63 - __clzll(mask);
        unsigned sufAbove = (unsigned)__shfl((int)p, L + 1, 64);
        if (L == 63) sufAbove = 0u;

        if (lane == L) {
            unsigned cum = sufAbove;
            int fb = L * 64;
            bool found = false;
            #pragma unroll
            for (int q = 15; q >= 0; --q) {       // descending bins: w,z,y,x
                cum += c[q].w; if (!found && cum >= K_CAND) { fb = L * 64 + q * 4 + 3; found = true; }
                cum += c[q].z; if (!found && cum >= K_CAND) { fb = L * 64 + q * 4 + 2; found = true; }
                cum += c[q].y; if (!found && cum >= K_CAND) { fb = L * 64 + q * 4 + 1; found = true; }
                cum += c[q].x; if (!found && cum >= K_CAND) { fb = L * 64 + q * 4 + 0; found = true; }
            }
            s_fb = fb;
        }
    }
    __syncthreads();
    const int FB = s_fb;

    // ---- append candidates ----
    if (bin >= FB) {
        unsigned pos = atomicAdd(cnt, 1u);
        if (pos < CAP) { gcs[pos] = s; gcidx[pos] = i; }
    }
    grid.sync();   // #3: candidate list complete
    if (bid != 0) return;

    // ================= tail: block 0 only =================
    const int M = (int)min(*cnt, (unsigned)CAP);
    float* ls   = pool;
    float* lx1  = pool + 512;
    float* ly1  = pool + 1024;
    float* lx2  = pool + 1536;
    float* ly2  = pool + 2048;
    float* lar  = pool + 2560;
    int*   llab = (int*)(pool + 3072);

    for (int c = tid; c < CAP; c += BT) {
        if (c < M) {
            int ai = gcidx[c];
            float sc = gcs[c];
            const float* lrow = logits + (long)ai * NCLS;
            float mm = lrow[0];
            int lab = 0;
            for (int j = 1; j < NCLS; ++j) {
                float v = lrow[j];
                if (v > mm) { mm = v; lab = j; }
            }
            float4 A = ((const float4*)anchors)[ai];
            float4 R = ((const float4*)boxreg)[ai];
            float cx = 0.5f * (A.x + A.z);
            float cy = 0.5f * (A.y + A.w);
            float ww = A.z - A.x;
            float hh = A.w - A.y;
            float X1 = cx - R.x * ww;
            float Y1 = cy - R.y * hh;
            float X2 = cx + R.z * ww;
            float Y2 = cy + R.w * hh;
            ls[c] = sc; lx1[c] = X1; ly1[c] = Y1; lx2[c] = X2; ly2[c] = Y2;
            lar[c] = fmaxf(X2 - X1, 0.0f) * fmaxf(Y2 - Y1, 0.0f);
            llab[c] = lab;
        } else {
            ls[c] = -INFINITY;
            lx1[c] = ly1[c] = lx2[c] = ly2[c] = 0.0f;
            lar[c] = 0.0f;
            llab[c] = 0;
        }
    }
    __syncthreads();

    // ---- greedy NMS, candidate state in LDS (no register-array spill) ----
    for (int it = 0; it < MAX_OUT; ++it) {
        float b = -INFINITY;
        int id = 0;
        for (int base = 0; base < CAP; base += BT) {
            int c = base + tid;              // stride-BT: conflict-free LDS
            float v = ls[c];
            if (v > b) { b = v; id = c; }
        }
        #pragma unroll
        for (int d = 32; d >= 1; d >>= 1) {
            float ob = __shfl_xor(b, d, 64);
            int   oid = __shfl_xor(id, d, 64);
            if (ob > b) { b = ob; id = oid; }
        }
        if (lane == 0) { s_best[w] = b; s_bid[w] = id; }
        __syncthreads();
        float gb = s_best[0];
        int gid = s_bid[0];
        if (s_best[1] > gb) { gb = s_best[1]; gid = s_bid[1]; }

        // winner box: same-address LDS reads broadcast (free)
        float sx1 = lx1[gid], sy1 = ly1[gid], sx2 = lx2[gid], sy2 = ly2[gid];
        float sar = lar[gid];
        int   slab = llab[gid];

        if (tid == 0) {
            out[it * 4 + 0] = sx1;
            out[it * 4 + 1] = sy1;
            out[it * 4 + 2] = sx2;
            out[it * 4 + 3] = sy2;
            out[4 * MAX_OUT + it] = (float)slab;
            out[5 * MAX_OUT + it] = gb;
        }

        // Lock: zero-area winner -> inter==0 with every box, self-iou=0/0=NaN,
        // NaN>0.6 false -> nothing suppressed -> reference re-selects this
        // same box for every remaining slot.
        if (sar == 0.0f) {
            for (int r = it + 1 + tid; r < MAX_OUT; r += BT) {
                out[r * 4 + 0] = sx1;
                out[r * 4 + 1] = sy1;
                out[r * 4 + 2] = sx2;
                out[r * 4 + 3] = sy2;
                out[4 * MAX_OUT + r] = (float)slab;
                out[5 * MAX_OUT + r] = gb;
            }
            return;
        }

        for (int base = 0; base < CAP; base += BT) {
            int c = base + tid;
            float ix1 = fmaxf(sx1, lx1[c]);
            float iy1 = fmaxf(sy1, ly1[c]);
            float ix2 = fminf(sx2, lx2[c]);
            float iy2 = fminf(sy2, ly2[c]);
            float inter = fmaxf(ix2 - ix1, 0.0f) * fmaxf(iy2 - iy1, 0.0f);
            float iou = inter / (sar + lar[c] - inter);
            if (iou > IOU_TH) ls[c] = -INFINITY;
        }
        __syncthreads();
    }
}

extern "C" void kernel_launch(void* const* d_in, const int* in_sizes, int n_in,
                              void* d_out, int out_size, void* d_ws, size_t ws_size,
                              hipStream_t stream) {
    const float* logits  = (const float*)d_in[0];
    const float* boxreg  = (const float*)d_in[1];
    const float* ctr     = (const float*)d_in[2];
    const float* anchors = (const float*)d_in[3];
    float* out = (float*)d_out;

    char* ws = (char*)d_ws;
    unsigned* hist  = (unsigned*)(ws + 0);
    unsigned* cnt   = (unsigned*)(ws + 16384);
    float*    gcs   = (float*)(ws + 16400);
    int*      gcidx = (int*)(ws + 18448);

    void* args[] = {
        (void*)&logits, (void*)&boxreg, (void*)&ctr, (void*)&anchors,
        (void*)&out, (void*)&hist, (void*)&cnt, (void*)&gcs, (void*)&gcidx
    };
    hipLaunchCooperativeKernel((void*)fcos_all_kernel, dim3(NB), dim3(BT),
                               args, 0, stream);
}

// Round 6
// 53.836 us; speedup vs baseline: 4.1228x; 4.1228x over previous
//
#include <hip/hip_runtime.h>
#include <math.h>

#define N_ANCH 87296
#define NCLS 91
#define NBINS 4096
#define K_CAND 256
#define CAP 512
#define MAX_OUT 100
#define IOU_TH 0.6f
#define NB1 682
#define BT1 128
#define NB2 682
#define BT2 128

// ws layout (bytes):
//      0: hist   (NBINS*4 = 16384)
//  16384: cnt    (4)
//  16388: done1  (4)
//  16392: done2  (4)
//  16396: fb     (4)
//  16400: cmeta  (CAP*16 = 8192)   {score, area, label, 0}
//  24592: cbox   (CAP*16 = 8192)
//  32784: scores (N_ANCH*4)
// memset zeroes [0, 16396): hist + cnt + done1 + done2.

__device__ __forceinline__ float sigmoidf_(float x) {
    return 1.0f / (1.0f + expf(-x));
}

// K1: score (wave-cooperative coalesced LDS staging) + global hist atomics +
// last-block threshold find (device-scope done-counter, no grid.sync).
__global__ void __launch_bounds__(BT1)
score_hist_kernel(const float* __restrict__ logits,
                  const float* __restrict__ ctr,
                  float* __restrict__ scores,
                  unsigned* __restrict__ hist,
                  unsigned* __restrict__ done1,
                  int* __restrict__ fb) {
    __shared__ float pool[2 * 64 * 91];   // 46592 B
    const int tid  = threadIdx.x;
    const int lane = tid & 63;
    const int w    = tid >> 6;
    const int bid  = blockIdx.x;

    const int rowbase = bid * BT1 + w * 64;
    const float4* g4 = (const float4*)logits + (size_t)rowbase * 91 / 4;
    float4* l4 = (float4*)(pool + w * 5824);
    #pragma unroll
    for (int k = 0; k < 23; ++k) {
        int idx = k * 64 + lane;
        if (idx < 1456) l4[idx] = g4[idx];
    }
    __syncthreads();

    const int i = bid * BT1 + tid;
    const float* row = pool + w * 5824 + lane * 91;
    float m = row[0];
    #pragma unroll
    for (int j = 1; j < NCLS; ++j) m = fmaxf(m, row[j]);
    const float s = sqrtf(sigmoidf_(m) * sigmoidf_(ctr[i]));
    scores[i] = s;
    const int bin = min(max((int)(s * (float)NBINS), 0), NBINS - 1);
    atomicAdd(&hist[bin], 1u);
    __syncthreads();   // barrier drains vmcnt: both waves' atomics complete

    // last-block threshold (wave 0 only; release covers whole block's stores
    // since both waves share this XCD's L2 and drained at the barrier above)
    if (w == 0) {
        unsigned old = 0;
        if (lane == 0)
            old = __hip_atomic_fetch_add(done1, 1u, __ATOMIC_ACQ_REL,
                                         __HIP_MEMORY_SCOPE_AGENT);
        old = (unsigned)__shfl((int)old, 0, 64);
        if (old == NB1 - 1) {
            unsigned d = __hip_atomic_load(done1, __ATOMIC_ACQUIRE,
                                           __HIP_MEMORY_SCOPE_AGENT);
            asm volatile("" :: "v"(d));   // keep the acquire load live

            const uint4* h4 = (const uint4*)hist;   // 1024 uint4
            uint4 c[16];
            #pragma unroll
            for (int q = 0; q < 16; ++q) c[q] = h4[lane * 16 + q];

            unsigned local = 0;
            #pragma unroll
            for (int q = 0; q < 16; ++q)
                local += c[q].x + c[q].y + c[q].z + c[q].w;

            unsigned p = local;                      // suffix-inclusive scan
            #pragma unroll
            for (int d2 = 1; d2 < 64; d2 <<= 1) {
                unsigned t = (unsigned)__shfl_down((int)p, d2, 64);
                if (lane + d2 < 64) p += t;
            }
            unsigned long long mask = __ballot(p >= K_CAND);
            int L = 63 - __clzll(mask);
            unsigned sufAbove = (unsigned)__shfl((int)p, L + 1, 64);
            if (L == 63) sufAbove = 0u;

            if (lane == L) {
                unsigned cum = sufAbove;
                int fbv = L * 64;
                bool found = false;
                #pragma unroll
                for (int q = 15; q >= 0; --q) {      // descending: w,z,y,x
                    cum += c[q].w; if (!found && cum >= K_CAND) { fbv = L * 64 + q * 4 + 3; found = true; }
                    cum += c[q].z; if (!found && cum >= K_CAND) { fbv = L * 64 + q * 4 + 2; found = true; }
                    cum += c[q].y; if (!found && cum >= K_CAND) { fbv = L * 64 + q * 4 + 1; found = true; }
                    cum += c[q].x; if (!found && cum >= K_CAND) { fbv = L * 64 + q * 4 + 0; found = true; }
                }
                *fb = fbv;
            }
        }
    }
}

// K2: parallel compact + decode; last block runs LDS NMS with NaN-lock.
__global__ void __launch_bounds__(BT2)
compact_nms_kernel(const float* __restrict__ logits,
                   const float* __restrict__ boxreg,
                   const float* __restrict__ anchors,
                   const float* __restrict__ scores,
                   const int* __restrict__ fb,
                   unsigned* __restrict__ cnt,
                   float4* __restrict__ cbox,
                   float4* __restrict__ cmeta,
                   unsigned* __restrict__ done2,
                   float* __restrict__ out) {
    __shared__ float ls[CAP], lx1[CAP], ly1[CAP], lx2[CAP], ly2[CAP], lar[CAP];
    __shared__ int   llab[CAP];
    __shared__ float s_best[2];
    __shared__ int   s_bid[2];
    __shared__ int   s_last;

    const int tid  = threadIdx.x;
    const int lane = tid & 63;
    const int w    = tid >> 6;
    const int bid  = blockIdx.x;

    const int i = bid * BT2 + tid;
    const float s = scores[i];
    const int bin = min(max((int)(s * (float)NBINS), 0), NBINS - 1);
    const int FB = *fb;
    if (bin >= FB) {
        unsigned pos = atomicAdd(cnt, 1u);
        if (pos < CAP) {
            const float* lrow = logits + (long)i * NCLS;
            float mm = lrow[0];
            int lab = 0;
            for (int j = 1; j < NCLS; ++j) {
                float v = lrow[j];
                if (v > mm) { mm = v; lab = j; }
            }
            float4 A = ((const float4*)anchors)[i];
            float4 R = ((const float4*)boxreg)[i];
            float cx = 0.5f * (A.x + A.z);
            float cy = 0.5f * (A.y + A.w);
            float ww = A.z - A.x;
            float hh = A.w - A.y;
            float X1 = cx - R.x * ww;
            float Y1 = cy - R.y * hh;
            float X2 = cx + R.z * ww;
            float Y2 = cy + R.w * hh;
            float4 bb; bb.x = X1; bb.y = Y1; bb.z = X2; bb.w = Y2;
            cbox[pos] = bb;
            float4 mt;
            mt.x = s;
            mt.y = fmaxf(X2 - X1, 0.0f) * fmaxf(Y2 - Y1, 0.0f);
            mt.z = (float)lab;
            mt.w = 0.0f;
            cmeta[pos] = mt;
        }
    }
    __syncthreads();   // drains both waves' stores/atomics (vmcnt 0 at barrier)

    if (tid == 0) {
        unsigned old = __hip_atomic_fetch_add(done2, 1u, __ATOMIC_ACQ_REL,
                                              __HIP_MEMORY_SCOPE_AGENT);
        s_last = (old == NB2 - 1) ? 1 : 0;
    }
    __syncthreads();
    if (!s_last) return;

    // acquire in every wave of the last block before reading candidate data
    {
        unsigned d = __hip_atomic_load(done2, __ATOMIC_ACQUIRE,
                                       __HIP_MEMORY_SCOPE_AGENT);
        asm volatile("" :: "v"(d));
    }
    const int M = (int)min(*cnt, (unsigned)CAP);

    for (int c = tid; c < CAP; c += BT2) {
        if (c < M) {
            float4 mt = cmeta[c];
            float4 bb = cbox[c];
            ls[c] = mt.x; lar[c] = mt.y; llab[c] = (int)mt.z;
            lx1[c] = bb.x; ly1[c] = bb.y; lx2[c] = bb.z; ly2[c] = bb.w;
        } else {
            ls[c] = -INFINITY;
            lx1[c] = ly1[c] = lx2[c] = ly2[c] = 0.0f;
            lar[c] = 0.0f;
            llab[c] = 0;
        }
    }
    __syncthreads();

    // greedy NMS (verified): LDS state, 2-wave argmax, NaN-lock shortcut
    for (int it = 0; it < MAX_OUT; ++it) {
        float b = -INFINITY;
        int id = 0;
        for (int base = 0; base < CAP; base += BT2) {
            int c = base + tid;              // stride-BT2: conflict-free
            float v = ls[c];
            if (v > b) { b = v; id = c; }
        }
        #pragma unroll
        for (int d = 32; d >= 1; d >>= 1) {
            float ob = __shfl_xor(b, d, 64);
            int   oid = __shfl_xor(id, d, 64);
            if (ob > b) { b = ob; id = oid; }
        }
        if (lane == 0) { s_best[w] = b; s_bid[w] = id; }
        __syncthreads();
        float gb = s_best[0];
        int gid = s_bid[0];
        if (s_best[1] > gb) { gb = s_best[1]; gid = s_bid[1]; }

        float sx1 = lx1[gid], sy1 = ly1[gid], sx2 = lx2[gid], sy2 = ly2[gid];
        float sar = lar[gid];
        int   slab = llab[gid];

        if (tid == 0) {
            out[it * 4 + 0] = sx1;
            out[it * 4 + 1] = sy1;
            out[it * 4 + 2] = sx2;
            out[it * 4 + 3] = sy2;
            out[4 * MAX_OUT + it] = (float)slab;
            out[5 * MAX_OUT + it] = gb;
        }

        // Lock: zero-area winner -> inter==0 with every box, self-iou=0/0=NaN,
        // NaN>0.6 false -> nothing suppressed -> reference re-selects this
        // same box for every remaining slot.
        if (sar == 0.0f) {
            for (int r = it + 1 + tid; r < MAX_OUT; r += BT2) {
                out[r * 4 + 0] = sx1;
                out[r * 4 + 1] = sy1;
                out[r * 4 + 2] = sx2;
                out[r * 4 + 3] = sy2;
                out[4 * MAX_OUT + r] = (float)slab;
                out[5 * MAX_OUT + r] = gb;
            }
            return;
        }

        for (int base = 0; base < CAP; base += BT2) {
            int c = base + tid;
            float ix1 = fmaxf(sx1, lx1[c]);
            float iy1 = fmaxf(sy1, ly1[c]);
            float ix2 = fminf(sx2, lx2[c]);
            float iy2 = fminf(sy2, ly2[c]);
            float inter = fmaxf(ix2 - ix1, 0.0f) * fmaxf(iy2 - iy1, 0.0f);
            float iou = inter / (sar + lar[c] - inter);
            if (iou > IOU_TH) ls[c] = -INFINITY;
        }
        __syncthreads();
    }
}

extern "C" void kernel_launch(void* const* d_in, const int* in_sizes, int n_in,
                              void* d_out, int out_size, void* d_ws, size_t ws_size,
                              hipStream_t stream) {
    const float* logits  = (const float*)d_in[0];
    const float* boxreg  = (const float*)d_in[1];
    const float* ctr     = (const float*)d_in[2];
    const float* anchors = (const float*)d_in[3];
    float* out = (float*)d_out;

    char* ws = (char*)d_ws;
    unsigned* hist   = (unsigned*)(ws + 0);
    unsigned* cnt    = (unsigned*)(ws + 16384);
    unsigned* done1  = (unsigned*)(ws + 16388);
    unsigned* done2  = (unsigned*)(ws + 16392);
    int*      fb     = (int*)(ws + 16396);
    float4*   cmeta  = (float4*)(ws + 16400);
    float4*   cbox   = (float4*)(ws + 24592);
    float*    scores = (float*)(ws + 32784);

    hipMemsetAsync(ws, 0, 16396, stream);
    score_hist_kernel<<<NB1, BT1, 0, stream>>>(logits, ctr, scores, hist, done1, fb);
    compact_nms_kernel<<<NB2, BT2, 0, stream>>>(logits, boxreg, anchors, scores,
                                                fb, cnt, cbox, cmeta, done2, out);
}

// Round 7
// 45.812 us; speedup vs baseline: 4.8450x; 1.1752x over previous
//
#include <hip/hip_runtime.h>
#include <math.h>

#define N_ANCH 87296
#define NCLS 91
#define NBINS 4096
#define K_CAND 256
#define CAP 512
#define MAX_OUT 100
#define IOU_TH 0.6f
#define NB1 682
#define BT1 128
#define T2 1024          // K2 threads (16 waves)

// ws layout (bytes):
//        0: hist   (NBINS*4 = 16384)          <- memset to 0 each call
//    16384: scores (N_ANCH*4 = 349184)        ends 365568
//   365568: pbox   (N_ANCH*16 = 1396736)      16B aligned; ends 1762304
//  1762304: pmeta  (N_ANCH*8 = 698368)        {area, label}

__device__ __forceinline__ float sigmoidf_(float x) {
    return 1.0f / (1.0f + expf(-x));
}

// K1: wave-cooperative coalesced LDS staging of 64 rows/wave; per-anchor
// score + label (first-max-wins, matching jnp.argmax) + box decode + area;
// global histogram atomicAdd.
__global__ void __launch_bounds__(BT1)
score_decode_kernel(const float* __restrict__ logits,
                    const float* __restrict__ boxreg,
                    const float* __restrict__ ctr,
                    const float* __restrict__ anchors,
                    float* __restrict__ scores,
                    float4* __restrict__ pbox,
                    float2* __restrict__ pmeta,
                    unsigned* __restrict__ hist) {
    __shared__ float pool[2 * 64 * 91];   // 46592 B
    const int tid  = threadIdx.x;
    const int lane = tid & 63;
    const int w    = tid >> 6;
    const int bid  = blockIdx.x;

    const int rowbase = bid * BT1 + w * 64;
    const float4* g4 = (const float4*)logits + (size_t)rowbase * 91 / 4;
    float4* l4 = (float4*)(pool + w * 5824);
    #pragma unroll
    for (int k = 0; k < 23; ++k) {
        int idx = k * 64 + lane;
        if (idx < 1456) l4[idx] = g4[idx];
    }
    __syncthreads();

    const int i = bid * BT1 + tid;
    const float* row = pool + w * 5824 + lane * 91;
    float m = row[0];
    int lab = 0;
    #pragma unroll
    for (int j = 1; j < NCLS; ++j) {
        float v = row[j];
        if (v > m) { m = v; lab = j; }   // strict > keeps FIRST max
    }
    const float s = sqrtf(sigmoidf_(m) * sigmoidf_(ctr[i]));
    scores[i] = s;

    // decode (coalesced float4 reads: 16B/lane consecutive)
    float4 A = ((const float4*)anchors)[i];
    float4 R = ((const float4*)boxreg)[i];
    float cx = 0.5f * (A.x + A.z);
    float cy = 0.5f * (A.y + A.w);
    float ww = A.z - A.x;
    float hh = A.w - A.y;
    float4 bb;
    bb.x = cx - R.x * ww;
    bb.y = cy - R.y * hh;
    bb.z = cx + R.z * ww;
    bb.w = cy + R.w * hh;
    pbox[i] = bb;
    float2 mt;
    mt.x = fmaxf(bb.z - bb.x, 0.0f) * fmaxf(bb.w - bb.y, 0.0f);
    mt.y = (float)lab;
    pmeta[i] = mt;

    const int bin = min(max((int)(s * (float)NBINS), 0), NBINS - 1);
    atomicAdd(&hist[bin], 1u);
}

// K2: single block. wave0: threshold bin from prebuilt hist (verified
// suffix-scan). One pass over scores -> LDS candidate append. Gather
// precomputed box/meta. Register-resident greedy NMS with NaN-lock shortcut.
__global__ void __launch_bounds__(T2)
select_nms_kernel(const unsigned* __restrict__ hist,
                  const float* __restrict__ scores,
                  const float4* __restrict__ pbox,
                  const float2* __restrict__ pmeta,
                  float* __restrict__ out) {
    __shared__ float    ls[CAP];
    __shared__ int      lidx[CAP];
    __shared__ unsigned cnt;
    __shared__ int      s_fb;
    __shared__ float    s_best[16];
    __shared__ int      s_bid[16];
    __shared__ float    s_box[5];
    __shared__ int      s_lab;

    const int tid  = threadIdx.x;
    const int lane = tid & 63;
    const int wid  = tid >> 6;

    if (tid == 0) cnt = 0u;

    // ---- threshold find (wave 0; verified logic) ----
    if (tid < 64) {
        const uint4* h4 = (const uint4*)hist;   // 1024 uint4
        uint4 c[16];
        #pragma unroll
        for (int q = 0; q < 16; ++q) c[q] = h4[lane * 16 + q];

        unsigned local = 0;
        #pragma unroll
        for (int q = 0; q < 16; ++q) local += c[q].x + c[q].y + c[q].z + c[q].w;

        unsigned p = local;                      // suffix-inclusive scan
        #pragma unroll
        for (int d = 1; d < 64; d <<= 1) {
            unsigned t = (unsigned)__shfl_down((int)p, d, 64);
            if (lane + d < 64) p += t;
        }
        unsigned long long mask = __ballot(p >= K_CAND);
        int L = 63 - __clzll(mask);
        unsigned sufAbove = (unsigned)__shfl((int)p, L + 1, 64);
        if (L == 63) sufAbove = 0u;

        if (lane == L) {
            unsigned cum = sufAbove;
            int fb = L * 64;
            bool found = false;
            #pragma unroll
            for (int q = 15; q >= 0; --q) {      // descending bins: w,z,y,x
                cum += c[q].w; if (!found && cum >= K_CAND) { fb = L * 64 + q * 4 + 3; found = true; }
                cum += c[q].z; if (!found && cum >= K_CAND) { fb = L * 64 + q * 4 + 2; found = true; }
                cum += c[q].y; if (!found && cum >= K_CAND) { fb = L * 64 + q * 4 + 1; found = true; }
                cum += c[q].x; if (!found && cum >= K_CAND) { fb = L * 64 + q * 4 + 0; found = true; }
            }
            s_fb = fb;
        }
    }
    __syncthreads();
    const int FB = s_fb;

    // ---- single pass: compact candidates >= FB ----
    const float4* s4 = (const float4*)scores;   // 21824 float4
    #pragma unroll
    for (int k = 0; k < 22; ++k) {
        int idx = k * T2 + tid;
        if (idx < N_ANCH / 4) {
            float4 v = s4[idx];
            float vv[4] = {v.x, v.y, v.z, v.w};
            #pragma unroll
            for (int c = 0; c < 4; ++c) {
                float s = vv[c];
                int b = min(max((int)(s * (float)NBINS), 0), NBINS - 1);
                if (b >= FB) {
                    unsigned pos = atomicAdd(&cnt, 1u);
                    if (pos < CAP) { ls[pos] = s; lidx[pos] = idx * 4 + c; }
                }
            }
        }
    }
    __syncthreads();
    const int M = (int)min(cnt, (unsigned)CAP);

    // ---- gather precomputed decode: thread t < M owns candidate t ----
    float SC, X1, Y1, X2, Y2, AR;
    int LAB;
    if (tid < M) {
        int ai = lidx[tid];
        SC = ls[tid];
        float4 bb = pbox[ai];
        float2 mt = pmeta[ai];
        X1 = bb.x; Y1 = bb.y; X2 = bb.z; Y2 = bb.w;
        AR = mt.x;
        LAB = (int)mt.y;
    } else {
        SC = -INFINITY;
        X1 = Y1 = X2 = Y2 = AR = 0.0f;
        LAB = 0;
    }
    __syncthreads();

    // ---- greedy NMS (verified register version, 16-wave argmax) ----
    for (int it = 0; it < MAX_OUT; ++it) {
        float b = SC;
        int id = tid;
        #pragma unroll
        for (int d = 32; d >= 1; d >>= 1) {
            float ob = __shfl_xor(b, d, 64);
            int   oid = __shfl_xor(id, d, 64);
            if (ob > b) { b = ob; id = oid; }
        }
        if (lane == 0) { s_best[wid] = b; s_bid[wid] = id; }
        __syncthreads();
        float gb = s_best[0];
        int gid = s_bid[0];
        #pragma unroll
        for (int w = 1; w < 16; ++w) {
            if (s_best[w] > gb) { gb = s_best[w]; gid = s_bid[w]; }
        }
        if (tid == gid) {
            s_box[0] = X1; s_box[1] = Y1; s_box[2] = X2; s_box[3] = Y2;
            s_box[4] = AR; s_lab = LAB;
        }
        __syncthreads();
        float sx1 = s_box[0], sy1 = s_box[1], sx2 = s_box[2], sy2 = s_box[3];
        float sar = s_box[4];
        int   slab = s_lab;

        if (tid == 0) {
            out[it * 4 + 0] = sx1;
            out[it * 4 + 1] = sy1;
            out[it * 4 + 2] = sx2;
            out[it * 4 + 3] = sy2;
            out[4 * MAX_OUT + it] = (float)slab;
            out[5 * MAX_OUT + it] = gb;
        }

        // Lock: zero-area winner -> inter==0 with every box, self-iou=0/0=NaN,
        // NaN>0.6 false -> nothing suppressed -> reference re-selects this
        // same box for every remaining slot.
        if (sar == 0.0f) {
            for (int r = it + 1 + tid; r < MAX_OUT; r += T2) {
                out[r * 4 + 0] = sx1;
                out[r * 4 + 1] = sy1;
                out[r * 4 + 2] = sx2;
                out[r * 4 + 3] = sy2;
                out[4 * MAX_OUT + r] = (float)slab;
                out[5 * MAX_OUT + r] = gb;
            }
            return;
        }

        float ix1 = fmaxf(sx1, X1);
        float iy1 = fmaxf(sy1, Y1);
        float ix2 = fminf(sx2, X2);
        float iy2 = fminf(sy2, Y2);
        float inter = fmaxf(ix2 - ix1, 0.0f) * fmaxf(iy2 - iy1, 0.0f);
        float iou = inter / (sar + AR - inter);
        if (iou > IOU_TH) SC = -INFINITY;
        __syncthreads();
    }
}

extern "C" void kernel_launch(void* const* d_in, const int* in_sizes, int n_in,
                              void* d_out, int out_size, void* d_ws, size_t ws_size,
                              hipStream_t stream) {
    const float* logits  = (const float*)d_in[0];
    const float* boxreg  = (const float*)d_in[1];
    const float* ctr     = (const float*)d_in[2];
    const float* anchors = (const float*)d_in[3];
    float* out = (float*)d_out;

    char* ws = (char*)d_ws;
    unsigned* hist   = (unsigned*)(ws + 0);
    float*    scores = (float*)(ws + 16384);
    float4*   pbox   = (float4*)(ws + 365568);
    float2*   pmeta  = (float2*)(ws + 1762304);

    hipMemsetAsync(ws, 0, 16384, stream);
    score_decode_kernel<<<NB1, BT1, 0, stream>>>(logits, boxreg, ctr, anchors,
                                                 scores, pbox, pmeta, hist);
    select_nms_kernel<<<1, T2, 0, stream>>>(hist, scores, pbox, pmeta, out);
}

// Round 8
// 30.745 us; speedup vs baseline: 7.2192x; 1.4900x over previous
//
#include <hip/hip_runtime.h>
#include <math.h>

#define N_ANCH 87296
#define NCLS 91
#define NBINS 4096
#define K_CAND 256
#define CAP 512
#define MAX_OUT 100
#define IOU_TH 0.6f
#define NB1 682
#define BT1 128
#define T2 1024          // K2 threads (16 waves)
#define NB16 10912       // N_ANCH*2B / 16B = uint4 count of bin array

// ws layout (bytes):
//        0: bins  (N_ANCH*2 = 174592)  u16 bin index per anchor
//   174592: pbox  (N_ANCH*16 = 1396736)  ends 1571328   (16B aligned)
//  1571328: pmeta (N_ANCH*16 = 1396736)  {area, label, score, 0}
// no memset required: every cell consumed is written by K1 first.

__device__ __forceinline__ float sigmoidf_(float x) {
    return 1.0f / (1.0f + expf(-x));
}

// K1: wave-cooperative coalesced LDS staging of 64 logit rows/wave;
// per-anchor score + label (first-max-wins) + box decode + area.
// Outputs: u16 bin, pbox float4, pmeta {area,label,score,0}.
__global__ void __launch_bounds__(BT1)
score_decode_kernel(const float* __restrict__ logits,
                    const float* __restrict__ boxreg,
                    const float* __restrict__ ctr,
                    const float* __restrict__ anchors,
                    unsigned short* __restrict__ bins,
                    float4* __restrict__ pbox,
                    float4* __restrict__ pmeta) {
    __shared__ float pool[2 * 64 * 91];   // 46592 B
    const int tid  = threadIdx.x;
    const int lane = tid & 63;
    const int w    = tid >> 6;
    const int bid  = blockIdx.x;

    const int rowbase = bid * BT1 + w * 64;
    const float4* g4 = (const float4*)logits + (size_t)rowbase * 91 / 4;
    float4* l4 = (float4*)(pool + w * 5824);
    #pragma unroll
    for (int k = 0; k < 23; ++k) {
        int idx = k * 64 + lane;
        if (idx < 1456) l4[idx] = g4[idx];
    }
    __syncthreads();

    const int i = bid * BT1 + tid;
    const float* row = pool + w * 5824 + lane * 91;
    float m = row[0];
    int lab = 0;
    #pragma unroll
    for (int j = 1; j < NCLS; ++j) {
        float v = row[j];
        if (v > m) { m = v; lab = j; }   // strict > keeps FIRST max (jnp.argmax)
    }
    const float s = sqrtf(sigmoidf_(m) * sigmoidf_(ctr[i]));
    const int bin = min(max((int)(s * (float)NBINS), 0), NBINS - 1);
    bins[i] = (unsigned short)bin;

    float4 A = ((const float4*)anchors)[i];
    float4 R = ((const float4*)boxreg)[i];
    float cx = 0.5f * (A.x + A.z);
    float cy = 0.5f * (A.y + A.w);
    float ww = A.z - A.x;
    float hh = A.w - A.y;
    float4 bb;
    bb.x = cx - R.x * ww;
    bb.y = cy - R.y * hh;
    bb.z = cx + R.z * ww;
    bb.w = cy + R.w * hh;
    pbox[i] = bb;
    float4 mt;
    mt.x = fmaxf(bb.z - bb.x, 0.0f) * fmaxf(bb.w - bb.y, 0.0f);
    mt.y = (float)lab;
    mt.z = s;
    mt.w = 0.0f;
    pmeta[i] = mt;
}

// K2: single WG. Bins loaded ONCE into registers (11 uint4/thread, static
// unroll) -> LDS hist -> wave0 suffix-scan threshold (verified) -> compact
// from registers -> 32B gather per candidate -> register NMS with NaN-lock.
__global__ void __launch_bounds__(T2)
select_nms_kernel(const unsigned short* __restrict__ bins,
                  const float4* __restrict__ pbox,
                  const float4* __restrict__ pmeta,
                  float* __restrict__ out) {
    __shared__ unsigned hist[NBINS];     // 16 KB
    __shared__ int      lidx[CAP];
    __shared__ unsigned cnt;
    __shared__ int      s_fb;
    __shared__ float    s_best[16];
    __shared__ int      s_bid[16];
    __shared__ float    s_box[5];
    __shared__ int      s_lab;

    const int tid  = threadIdx.x;
    const int lane = tid & 63;
    const int wid  = tid >> 6;

    for (int b = tid; b < NBINS; b += T2) hist[b] = 0u;
    if (tid == 0) cnt = 0u;
    __syncthreads();

    // ---- single global read: bins -> registers ----
    const uint4* b4 = (const uint4*)bins;   // NB16 uint4
    uint4 bv[11];
    #pragma unroll
    for (int k = 0; k < 11; ++k) {
        int idx = k * T2 + tid;
        if (idx < NB16) {
            bv[k] = b4[idx];
        } else {
            uint4 z; z.x = z.y = z.z = z.w = 0u;   // bin 0 sentinel: inert
            bv[k] = z;
        }
    }

    // ---- hist from registers (LDS atomics) ----
    #pragma unroll
    for (int k = 0; k < 11; ++k) {
        unsigned vv[4] = {bv[k].x, bv[k].y, bv[k].z, bv[k].w};
        #pragma unroll
        for (int j = 0; j < 4; ++j) {
            atomicAdd(&hist[vv[j] & 0xFFFFu], 1u);
            atomicAdd(&hist[vv[j] >> 16], 1u);
        }
    }
    __syncthreads();

    // ---- threshold find (wave 0; verified suffix-scan) ----
    if (tid < 64) {
        const uint4* h4 = (const uint4*)hist;   // 1024 uint4
        uint4 c[16];
        #pragma unroll
        for (int q = 0; q < 16; ++q) c[q] = h4[lane * 16 + q];

        unsigned local = 0;
        #pragma unroll
        for (int q = 0; q < 16; ++q) local += c[q].x + c[q].y + c[q].z + c[q].w;

        unsigned p = local;                      // suffix-inclusive scan
        #pragma unroll
        for (int d = 1; d < 64; d <<= 1) {
            unsigned t = (unsigned)__shfl_down((int)p, d, 64);
            if (lane + d < 64) p += t;
        }
        unsigned long long mask = __ballot(p >= K_CAND);
        int L = 63 - __clzll(mask);
        unsigned sufAbove = (unsigned)__shfl((int)p, L + 1, 64);
        if (L == 63) sufAbove = 0u;

        if (lane == L) {
            unsigned cum = sufAbove;
            int fb = L * 64;
            bool found = false;
            #pragma unroll
            for (int q = 15; q >= 0; --q) {      // descending bins: w,z,y,x
                cum += c[q].w; if (!found && cum >= K_CAND) { fb = L * 64 + q * 4 + 3; found = true; }
                cum += c[q].z; if (!found && cum >= K_CAND) { fb = L * 64 + q * 4 + 2; found = true; }
                cum += c[q].y; if (!found && cum >= K_CAND) { fb = L * 64 + q * 4 + 1; found = true; }
                cum += c[q].x; if (!found && cum >= K_CAND) { fb = L * 64 + q * 4 + 0; found = true; }
            }
            s_fb = fb;
        }
    }
    __syncthreads();
    const unsigned FB = (unsigned)s_fb;

    // ---- compact from registers ----
    #pragma unroll
    for (int k = 0; k < 11; ++k) {
        int idx = k * T2 + tid;
        if (idx < NB16) {
            unsigned vv[4] = {bv[k].x, bv[k].y, bv[k].z, bv[k].w};
            #pragma unroll
            for (int j = 0; j < 4; ++j) {
                unsigned lo = vv[j] & 0xFFFFu;
                unsigned hi = vv[j] >> 16;
                if (lo >= FB) {
                    unsigned pos = atomicAdd(&cnt, 1u);
                    if (pos < CAP) lidx[pos] = idx * 8 + 2 * j;
                }
                if (hi >= FB) {
                    unsigned pos = atomicAdd(&cnt, 1u);
                    if (pos < CAP) lidx[pos] = idx * 8 + 2 * j + 1;
                }
            }
        }
    }
    __syncthreads();
    const int M = (int)min(cnt, (unsigned)CAP);

    // ---- gather precomputed decode: thread t < M owns candidate t ----
    float SC, X1, Y1, X2, Y2, AR;
    int LAB;
    if (tid < M) {
        int ai = lidx[tid];
        float4 bb = pbox[ai];
        float4 mt = pmeta[ai];
        X1 = bb.x; Y1 = bb.y; X2 = bb.z; Y2 = bb.w;
        AR = mt.x;
        LAB = (int)mt.y;
        SC = mt.z;
    } else {
        SC = -INFINITY;
        X1 = Y1 = X2 = Y2 = AR = 0.0f;
        LAB = 0;
    }
    __syncthreads();

    // ---- greedy NMS (verified register version, 16-wave argmax) ----
    for (int it = 0; it < MAX_OUT; ++it) {
        float b = SC;
        int id = tid;
        #pragma unroll
        for (int d = 32; d >= 1; d >>= 1) {
            float ob = __shfl_xor(b, d, 64);
            int   oid = __shfl_xor(id, d, 64);
            if (ob > b) { b = ob; id = oid; }
        }
        if (lane == 0) { s_best[wid] = b; s_bid[wid] = id; }
        __syncthreads();
        float gb = s_best[0];
        int gid = s_bid[0];
        #pragma unroll
        for (int w = 1; w < 16; ++w) {
            if (s_best[w] > gb) { gb = s_best[w]; gid = s_bid[w]; }
        }
        if (tid == gid) {
            s_box[0] = X1; s_box[1] = Y1; s_box[2] = X2; s_box[3] = Y2;
            s_box[4] = AR; s_lab = LAB;
        }
        __syncthreads();
        float sx1 = s_box[0], sy1 = s_box[1], sx2 = s_box[2], sy2 = s_box[3];
        float sar = s_box[4];
        int   slab = s_lab;

        if (tid == 0) {
            out[it * 4 + 0] = sx1;
            out[it * 4 + 1] = sy1;
            out[it * 4 + 2] = sx2;
            out[it * 4 + 3] = sy2;
            out[4 * MAX_OUT + it] = (float)slab;
            out[5 * MAX_OUT + it] = gb;
        }

        // Lock: zero-area winner -> inter==0 with every box, self-iou=0/0=NaN,
        // NaN>0.6 false -> nothing suppressed -> reference re-selects this
        // same box for every remaining slot.
        if (sar == 0.0f) {
            for (int r = it + 1 + tid; r < MAX_OUT; r += T2) {
                out[r * 4 + 0] = sx1;
                out[r * 4 + 1] = sy1;
                out[r * 4 + 2] = sx2;
                out[r * 4 + 3] = sy2;
                out[4 * MAX_OUT + r] = (float)slab;
                out[5 * MAX_OUT + r] = gb;
            }
            return;
        }

        float ix1 = fmaxf(sx1, X1);
        float iy1 = fmaxf(sy1, Y1);
        float ix2 = fminf(sx2, X2);
        float iy2 = fminf(sy2, Y2);
        float inter = fmaxf(ix2 - ix1, 0.0f) * fmaxf(iy2 - iy1, 0.0f);
        float iou = inter / (sar + AR - inter);
        if (iou > IOU_TH) SC = -INFINITY;
        __syncthreads();
    }
}

extern "C" void kernel_launch(void* const* d_in, const int* in_sizes, int n_in,
                              void* d_out, int out_size, void* d_ws, size_t ws_size,
                              hipStream_t stream) {
    const float* logits  = (const float*)d_in[0];
    const float* boxreg  = (const float*)d_in[1];
    const float* ctr     = (const float*)d_in[2];
    const float* anchors = (const float*)d_in[3];
    float* out = (float*)d_out;

    char* ws = (char*)d_ws;
    unsigned short* bins = (unsigned short*)(ws + 0);
    float4*         pbox = (float4*)(ws + 174592);
    float4*         pmeta= (float4*)(ws + 1571328);

    score_decode_kernel<<<NB1, BT1, 0, stream>>>(logits, boxreg, ctr, anchors,
                                                 bins, pbox, pmeta);
    select_nms_kernel<<<1, T2, 0, stream>>>(bins, pbox, pmeta, out);
}

// Round 9
// 30.385 us; speedup vs baseline: 7.3047x; 1.0118x over previous
//
#include <hip/hip_runtime.h>
#include <math.h>

#define N_ANCH 87296
#define NCLS 91
#define NBINS 4096
#define K_CAND 256
#define CAP 512
#define MAX_OUT 100
#define IOU_TH 0.6f
#define NB1 682
#define BT1 128
#define T2 1024          // K2 threads (16 waves)
#define NB16 10912       // N_ANCH*2B / 16B = uint4 count of bin array

// ws layout (bytes):
//        0: bins  (N_ANCH*2 = 174592)  u16 bin index per anchor
//   174592: pbox  (N_ANCH*16 = 1396736)  ends 1571328   (16B aligned)
//  1571328: pmeta (N_ANCH*16 = 1396736)  {area, label, score, 0}
// no memset required: every cell consumed is written by K1 first.

__device__ __forceinline__ float sigmoidf_(float x) {
    return 1.0f / (1.0f + expf(-x));
}

// K1: per-anchor score + label + box decode. Wave-private LDS staging in
// 4 chunks of 16 rows (5.8 KB/wave, NO barriers): stage 364 float4 coalesced,
// lane l reduces local row (l&15), col-quarter (l>>4) tracking (max,idx),
// shfl_xor(16)+shfl_xor(32) combine -> every lane has full row result; lane
// keeps chunk (l>>4). 11.6 KB LDS/block + launch_bounds(128,4) -> 16 waves/CU.
__global__ void __launch_bounds__(BT1, 4)
score_decode_kernel(const float* __restrict__ logits,
                    const float* __restrict__ boxreg,
                    const float* __restrict__ ctr,
                    const float* __restrict__ anchors,
                    unsigned short* __restrict__ bins,
                    float4* __restrict__ pbox,
                    float4* __restrict__ pmeta) {
    __shared__ float pool[2 * 16 * 91];   // 2 waves x 1456 floats = 11648 B
    const int tid  = threadIdx.x;
    const int lane = tid & 63;
    const int w    = tid >> 6;
    const int bid  = blockIdx.x;
    const int wavebase = bid * BT1 + w * 64;

    float*  buf = pool + w * 1456;
    float4* l4  = (float4*)buf;

    const int r  = lane & 15;            // local row within a chunk
    const int q  = lane >> 4;            // column quarter
    const int q0 = q * 23;
    const int qn = (q == 3) ? 22 : 23;   // quarters: [0,23)[23,46)[46,69)[69,91)

    float m = -INFINITY;                 // own anchor's max logit
    int   lab = 0;                       // own anchor's argmax (first-max)

    #pragma unroll
    for (int c = 0; c < 4; ++c) {
        // stage 16 rows = 1456 floats = 364 float4 (coalesced, 16B-aligned)
        const float4* g4 = (const float4*)logits +
                           ((size_t)(wavebase + c * 16) * 91) / 4;
        #pragma unroll
        for (int k = 0; k < 6; ++k) {
            int idx = k * 64 + lane;
            if (idx < 364) l4[idx] = g4[idx];
        }
        // same-wave DS ordering + lgkmcnt: no barrier needed (wave-private buf)
        const float* rp = buf + r * 91 + q0;
        float cm = rp[0];
        int   ci = q0;
        #pragma unroll
        for (int j = 1; j < 23; ++j) {
            if (j < qn) {
                float v = rp[j];
                if (v > cm) { cm = v; ci = q0 + j; }   // strict >: first max
            }
        }
        // combine 4 quarters; on tie keep lower index (jnp.argmax first-max)
        float om = __shfl_xor(cm, 16, 64);
        int   oi = __shfl_xor(ci, 16, 64);
        if (om > cm || (om == cm && oi < ci)) { cm = om; ci = oi; }
        om = __shfl_xor(cm, 32, 64);
        oi = __shfl_xor(ci, 32, 64);
        if (om > cm || (om == cm && oi < ci)) { cm = om; ci = oi; }

        if (c == (lane >> 4)) { m = cm; lab = ci; }   // own row = own chunk
    }

    const int i = wavebase + lane;
    const float s = sqrtf(sigmoidf_(m) * sigmoidf_(ctr[i]));
    const int bin = min(max((int)(s * (float)NBINS), 0), NBINS - 1);
    bins[i] = (unsigned short)bin;

    float4 A = ((const float4*)anchors)[i];
    float4 R = ((const float4*)boxreg)[i];
    float cx = 0.5f * (A.x + A.z);
    float cy = 0.5f * (A.y + A.w);
    float ww = A.z - A.x;
    float hh = A.w - A.y;
    float4 bb;
    bb.x = cx - R.x * ww;
    bb.y = cy - R.y * hh;
    bb.z = cx + R.z * ww;
    bb.w = cy + R.w * hh;
    pbox[i] = bb;
    float4 mt;
    mt.x = fmaxf(bb.z - bb.x, 0.0f) * fmaxf(bb.w - bb.y, 0.0f);
    mt.y = (float)lab;
    mt.z = s;
    mt.w = 0.0f;
    pmeta[i] = mt;
}

// K2: single WG (verified r8 kernel). Bins loaded ONCE into registers ->
// LDS hist -> wave0 suffix-scan threshold -> compact from registers ->
// 32B gather per candidate -> register NMS with NaN-lock shortcut.
__global__ void __launch_bounds__(T2)
select_nms_kernel(const unsigned short* __restrict__ bins,
                  const float4* __restrict__ pbox,
                  const float4* __restrict__ pmeta,
                  float* __restrict__ out) {
    __shared__ unsigned hist[NBINS];     // 16 KB
    __shared__ int      lidx[CAP];
    __shared__ unsigned cnt;
    __shared__ int      s_fb;
    __shared__ float    s_best[16];
    __shared__ int      s_bid[16];
    __shared__ float    s_box[5];
    __shared__ int      s_lab;

    const int tid  = threadIdx.x;
    const int lane = tid & 63;
    const int wid  = tid >> 6;

    for (int b = tid; b < NBINS; b += T2) hist[b] = 0u;
    if (tid == 0) cnt = 0u;
    __syncthreads();

    // ---- single global read: bins -> registers ----
    const uint4* b4 = (const uint4*)bins;   // NB16 uint4
    uint4 bv[11];
    #pragma unroll
    for (int k = 0; k < 11; ++k) {
        int idx = k * T2 + tid;
        if (idx < NB16) {
            bv[k] = b4[idx];
        } else {
            uint4 z; z.x = z.y = z.z = z.w = 0u;   // bin 0 sentinel: inert
            bv[k] = z;
        }
    }

    // ---- hist from registers (LDS atomics) ----
    #pragma unroll
    for (int k = 0; k < 11; ++k) {
        unsigned vv[4] = {bv[k].x, bv[k].y, bv[k].z, bv[k].w};
        #pragma unroll
        for (int j = 0; j < 4; ++j) {
            atomicAdd(&hist[vv[j] & 0xFFFFu], 1u);
            atomicAdd(&hist[vv[j] >> 16], 1u);
        }
    }
    __syncthreads();

    // ---- threshold find (wave 0; verified suffix-scan) ----
    if (tid < 64) {
        const uint4* h4 = (const uint4*)hist;   // 1024 uint4
        uint4 c[16];
        #pragma unroll
        for (int q = 0; q < 16; ++q) c[q] = h4[lane * 16 + q];

        unsigned local = 0;
        #pragma unroll
        for (int q = 0; q < 16; ++q) local += c[q].x + c[q].y + c[q].z + c[q].w;

        unsigned p = local;                      // suffix-inclusive scan
        #pragma unroll
        for (int d = 1; d < 64; d <<= 1) {
            unsigned t = (unsigned)__shfl_down((int)p, d, 64);
            if (lane + d < 64) p += t;
        }
        unsigned long long mask = __ballot(p >= K_CAND);
        int L = 63 - __clzll(mask);
        unsigned sufAbove = (unsigned)__shfl((int)p, L + 1, 64);
        if (L == 63) sufAbove = 0u;

        if (lane == L) {
            unsigned cum = sufAbove;
            int fb = L * 64;
            bool found = false;
            #pragma unroll
            for (int q = 15; q >= 0; --q) {      // descending bins: w,z,y,x
                cum += c[q].w; if (!found && cum >= K_CAND) { fb = L * 64 + q * 4 + 3; found = true; }
                cum += c[q].z; if (!found && cum >= K_CAND) { fb = L * 64 + q * 4 + 2; found = true; }
                cum += c[q].y; if (!found && cum >= K_CAND) { fb = L * 64 + q * 4 + 1; found = true; }
                cum += c[q].x; if (!found && cum >= K_CAND) { fb = L * 64 + q * 4 + 0; found = true; }
            }
            s_fb = fb;
        }
    }
    __syncthreads();
    const unsigned FB = (unsigned)s_fb;

    // ---- compact from registers ----
    #pragma unroll
    for (int k = 0; k < 11; ++k) {
        int idx = k * T2 + tid;
        if (idx < NB16) {
            unsigned vv[4] = {bv[k].x, bv[k].y, bv[k].z, bv[k].w};
            #pragma unroll
            for (int j = 0; j < 4; ++j) {
                unsigned lo = vv[j] & 0xFFFFu;
                unsigned hi = vv[j] >> 16;
                if (lo >= FB) {
                    unsigned pos = atomicAdd(&cnt, 1u);
                    if (pos < CAP) lidx[pos] = idx * 8 + 2 * j;
                }
                if (hi >= FB) {
                    unsigned pos = atomicAdd(&cnt, 1u);
                    if (pos < CAP) lidx[pos] = idx * 8 + 2 * j + 1;
                }
            }
        }
    }
    __syncthreads();
    const int M = (int)min(cnt, (unsigned)CAP);

    // ---- gather precomputed decode: thread t < M owns candidate t ----
    float SC, X1, Y1, X2, Y2, AR;
    int LAB;
    if (tid < M) {
        int ai = lidx[tid];
        float4 bb = pbox[ai];
        float4 mt = pmeta[ai];
        X1 = bb.x; Y1 = bb.y; X2 = bb.z; Y2 = bb.w;
        AR = mt.x;
        LAB = (int)mt.y;
        SC = mt.z;
    } else {
        SC = -INFINITY;
        X1 = Y1 = X2 = Y2 = AR = 0.0f;
        LAB = 0;
    }
    __syncthreads();

    // ---- greedy NMS (verified register version, 16-wave argmax) ----
    for (int it = 0; it < MAX_OUT; ++it) {
        float b = SC;
        int id = tid;
        #pragma unroll
        for (int d = 32; d >= 1; d >>= 1) {
            float ob = __shfl_xor(b, d, 64);
            int   oid = __shfl_xor(id, d, 64);
            if (ob > b) { b = ob; id = oid; }
        }
        if (lane == 0) { s_best[wid] = b; s_bid[wid] = id; }
        __syncthreads();
        float gb = s_best[0];
        int gid = s_bid[0];
        #pragma unroll
        for (int w = 1; w < 16; ++w) {
            if (s_best[w] > gb) { gb = s_best[w]; gid = s_bid[w]; }
        }
        if (tid == gid) {
            s_box[0] = X1; s_box[1] = Y1; s_box[2] = X2; s_box[3] = Y2;
            s_box[4] = AR; s_lab = LAB;
        }
        __syncthreads();
        float sx1 = s_box[0], sy1 = s_box[1], sx2 = s_box[2], sy2 = s_box[3];
        float sar = s_box[4];
        int   slab = s_lab;

        if (tid == 0) {
            out[it * 4 + 0] = sx1;
            out[it * 4 + 1] = sy1;
            out[it * 4 + 2] = sx2;
            out[it * 4 + 3] = sy2;
            out[4 * MAX_OUT + it] = (float)slab;
            out[5 * MAX_OUT + it] = gb;
        }

        // Lock: zero-area winner -> inter==0 with every box, self-iou=0/0=NaN,
        // NaN>0.6 false -> nothing suppressed -> reference re-selects this
        // same box for every remaining slot.
        if (sar == 0.0f) {
            for (int r = it + 1 + tid; r < MAX_OUT; r += T2) {
                out[r * 4 + 0] = sx1;
                out[r * 4 + 1] = sy1;
                out[r * 4 + 2] = sx2;
                out[r * 4 + 3] = sy2;
                out[4 * MAX_OUT + r] = (float)slab;
                out[5 * MAX_OUT + r] = gb;
            }
            return;
        }

        float ix1 = fmaxf(sx1, X1);
        float iy1 = fmaxf(sy1, Y1);
        float ix2 = fminf(sx2, X2);
        float iy2 = fminf(sy2, Y2);
        float inter = fmaxf(ix2 - ix1, 0.0f) * fmaxf(iy2 - iy1, 0.0f);
        float iou = inter / (sar + AR - inter);
        if (iou > IOU_TH) SC = -INFINITY;
        __syncthreads();
    }
}

extern "C" void kernel_launch(void* const* d_in, const int* in_sizes, int n_in,
                              void* d_out, int out_size, void* d_ws, size_t ws_size,
                              hipStream_t stream) {
    const float* logits  = (const float*)d_in[0];
    const float* boxreg  = (const float*)d_in[1];
    const float* ctr     = (const float*)d_in[2];
    const float* anchors = (const float*)d_in[3];
    float* out = (float*)d_out;

    char* ws = (char*)d_ws;
    unsigned short* bins = (unsigned short*)(ws + 0);
    float4*         pbox = (float4*)(ws + 174592);
    float4*         pmeta= (float4*)(ws + 1571328);

    score_decode_kernel<<<NB1, BT1, 0, stream>>>(logits, boxreg, ctr, anchors,
                                                 bins, pbox, pmeta);
    select_nms_kernel<<<1, T2, 0, stream>>>(bins, pbox, pmeta, out);
}